// Round 8
// baseline (383.940 us; speedup 1.0000x reference)
//
#include <hip/hip_runtime.h>

#define H 32
#define SEQ 512
#define BM 16          // batch rows per block = 4 waves x 4 rows
#define NTHREADS 256   // 4 waves, 1/SIMD; each wave self-contained: 4 rows, BOTH layers
#define HSTRIDE 40     // halves per h-row: 80B rows, 16B-aligned b128 frags

typedef _Float16 half8 __attribute__((ext_vector_type(8)));
typedef _Float16 f16x2 __attribute__((ext_vector_type(2)));
typedef __attribute__((ext_vector_type(4))) float f32x4;
typedef __attribute__((ext_vector_type(2))) float f32x2;

#define L2E 1.44269504088896340736f

__device__ __forceinline__ float rcp_(float x)  { return __builtin_amdgcn_rcpf(x); }
__device__ __forceinline__ float exp2_(float x) { return __builtin_amdgcn_exp2f(x); }  // raw v_exp_f32
#define MFMA16(A, B, C) __builtin_amdgcn_mfma_f32_16x16x32_f16((A), (B), (C), 0, 0, 0)

// Two LSTM cells as a packed pair (v_pk_* f32); per-element numerics identical to
// the verified scalar cell (5 v_exp + 2 v_rcp each). Verified R5/R7.
__device__ __forceinline__ f32x2 cell2(const f32x4& ga, const f32x4& gb, f32x2& cst) {
    f32x2 ei = {exp2_(ga[0]), exp2_(gb[0])};
    f32x2 ef = {exp2_(ga[1]), exp2_(gb[1])};
    f32x2 eg = {exp2_(ga[2]), exp2_(gb[2])};
    f32x2 eo = {exp2_(ga[3]), exp2_(gb[3])};
    f32x2 A  = 1.f + ei, F = 1.f + ef;
    f32x2 Gp = eg + 1.f, Gm = eg - 1.f;
    f32x2 t1 = A * Gp;
    f32x2 num = __builtin_elementwise_fma(cst, t1, Gm * F);
    f32x2 den = F * t1;
    f32x2 r1 = {rcp_(den.x), rcp_(den.y)};
    f32x2 cn = num * r1;
    cst = cn;
    f32x2 arg = __builtin_elementwise_min(cn * (2.f * L2E), (f32x2)80.f);
    f32x2 ec = {exp2_(arg.x), exp2_(arg.y)};
    f32x2 dh = (1.f + eo) * (ec + 1.f);
    f32x2 r2 = {rcp_(dh.x), rcp_(dh.y)};
    return (ec - 1.f) * r2;
}

// Select one f32x4 out of 4 by 2-bit lane-varying index (s1:s0): 12 v_cndmask.
__device__ __forceinline__ f32x4 sel4(const f32x4& a0, const f32x4& a1,
                                      const f32x4& a2, const f32x4& a3,
                                      bool s0, bool s1) {
    f32x4 r;
    #pragma unroll
    for (int j = 0; j < 4; ++j) {
        float t0 = s0 ? a1[j] : a0[j];
        float t1 = s0 ? a3[j] : a2[j];
        r[j] = s1 ? t1 : t0;
    }
    return r;
}

__global__ __launch_bounds__(NTHREADS, 1) void lstm_kernel(
    const float* __restrict__ x,      // [4096,512]
    const float* __restrict__ w_ih0,  // [128,1]
    const float* __restrict__ w_hh0,  // [128,32]
    const float* __restrict__ b_ih0, const float* __restrict__ b_hh0,
    const float* __restrict__ w_ih1,  // [128,32]
    const float* __restrict__ w_hh1,  // [128,32]
    const float* __restrict__ b_ih1, const float* __restrict__ b_hh1,
    const float* __restrict__ fc1_w,  // [16,32]
    const float* __restrict__ fc1_b,  // [16]
    const float* __restrict__ fc2_w,  // [1,16]
    const float* __restrict__ fc2_b,  // [1]
    float* __restrict__ out)          // [4096]
{
    __shared__ __align__(16) float    xbufT[(SEQ + 1) * BM];      // 32.8 KB, [step][row]
    __shared__ __align__(16) _Float16 h1s[2][BM * HSTRIDE];       // ping-pong h1 (wave-private rows)
    __shared__ __align__(16) _Float16 h2s[2][BM * HSTRIDE];       // ping-pong h2 (wave-private rows)
    __shared__ __align__(16) float    h2f[BM * 33];
    __shared__ __align__(16) float    yb[BM * 17];

    const int tid  = threadIdx.x;
    const int lane = tid & 63;
    const int wv   = tid >> 6;          // wave id 0..3 (one per SIMD)
    const int c    = lane & 15;         // MFMA column: row = c&3, dup index s = c>>2
    const int q    = lane >> 4;         // k-quad / D row-group
    const int s    = c >> 2;            // kept MFMA pair {2s, 2s+1} -> units 8s+2q+{0,1}
    const bool sb0 = s & 1, sb1 = (s >> 1) & 1;
    const int row  = 4 * wv + (c & 3);  // this lane's batch row within the block
    const int r0   = blockIdx.x * BM;

    // ---- stage x transposed: xbufT[s][row] ----
    {
        const int xrow = tid >> 4;          // 0..15
        const int s0_  = (tid & 15) * 32;   // 32 steps per thread
        const float* xr = x + (size_t)(r0 + xrow) * SEQ + s0_;
        #pragma unroll
        for (int i = 0; i < 32; i += 4) {
            float4 v = *(const float4*)&xr[i];
            xbufT[(s0_ + i + 0) * BM + xrow] = v.x;
            xbufT[(s0_ + i + 1) * BM + xrow] = v.y;
            xbufT[(s0_ + i + 2) * BM + xrow] = v.z;
            xbufT[(s0_ + i + 3) * BM + xrow] = v.w;
        }
    }
    for (int i = tid; i < 2 * BM * HSTRIDE; i += NTHREADS) {
        ((_Float16*)h1s)[i] = (_Float16)0.f;
        ((_Float16*)h2s)[i] = (_Float16)0.f;
    }

    // ---- W fragments. MFMA kk (0..7) of each matvec: A-row r holds W row
    // (gate r&3, unit 8*(kk>>1) + 2*(r>>2) + (kk&1)). At lane (c,q), MFMA kk's D =
    // gates 0-3 of unit 8*(kk>>1)+2q+(kk&1), batch row c&3 (cols = 4 rows x 4 dup).
    // Lane keeps kk = 2s, 2s+1 -> ADJACENT units 8s+2q, 8s+2q+1 -> half2 write.
    // Gate scales folded (i,f,o: -L2E ; g: +2L2E) so cells use raw v_exp_f32.
    const float gsc[4] = { -L2E, -L2E, 2.f * L2E, -L2E };
    const float wsc = gsc[c & 3];
    const int kb = 8 * q;

    half8 wA0[8], wI1[8], wH1[8];       // w_hh0 / w_ih1 / w_hh1 fragments
    #pragma unroll
    for (int kk = 0; kk < 8; ++kk) {
        const int worig = (c & 3) * H + 8 * (kk >> 1) + 2 * (c >> 2) + (kk & 1);
        const float* p = &w_hh0[worig * H + kb];
        #pragma unroll
        for (int j = 0; j < 8; ++j) wA0[kk][j] = (_Float16)(p[j] * wsc);
        p = &w_ih1[worig * H + kb];
        #pragma unroll
        for (int j = 0; j < 8; ++j) wI1[kk][j] = (_Float16)(p[j] * wsc);
        p = &w_hh1[worig * H + kb];
        #pragma unroll
        for (int j = 0; j < 8; ++j) wH1[kk][j] = (_Float16)(p[j] * wsc);
    }
    f32x4 b1v[2], wxv[2], b2v[2];       // per-lane cell params, units u(k) = 8s+2q+k
    #pragma unroll
    for (int k = 0; k < 2; ++k) {
        const int u = 8 * s + 2 * q + k;
        #pragma unroll
        for (int g = 0; g < 4; ++g) {
            b1v[k][g] = (b_ih0[g * H + u] + b_hh0[g * H + u]) * gsc[g];
            wxv[k][g] = w_ih0[g * H + u] * gsc[g];
            b2v[k][g] = (b_ih1[g * H + u] + b_hh1[g * H + u]) * gsc[g];
        }
    }

    f32x2 cst1 = {0.f, 0.f}, cst2 = {0.f, 0.f};
    f32x2 hl = {0.f, 0.f};              // h2(511) pair
    f32x4 Pf[8] = {};                   // register-carried P(tau) = W_ih1@h1(tau)+b

    const int fofs  = row * HSTRIDE + kb;              // b128 frag read (halves)
    const int whofs = row * HSTRIDE + 8 * s + 2 * q;   // half2 h write (halves, even)

    __syncthreads();                    // staging done; NO barriers in the loop below

    float xv = xbufT[row];              // prefetched x(t=0)

    // Iteration t (all per-wave, no cross-wave deps): L1 computes h1(t) (t<512);
    // L2 finishes tau=t-2 using Pf from iter t-1 and h2(t-3); then Pf := P(t-1)
    // from the already-loaded B1 = h1(t-1). Ping-pong slots: h1 write t&1, read
    // (t-1)&1; h2 write (t-2)&1 = t&1, read (t-3)&1 = (t&1)^1.
    auto step = [&](int t, int P, bool doL1, bool doL2, bool doP) {
        half8 B1 = *(const half8*)(&h1s[P ^ 1][0] + fofs);   // h1(t-1)
        half8 B2 = *(const half8*)(&h2s[P ^ 1][0] + fofs);   // h2(t-3)
        if (doL2) {
            f32x4 a[8];
            #pragma unroll
            for (int kk = 0; kk < 8; ++kk) a[kk] = MFMA16(wH1[kk], B2, Pf[kk]);
            f32x4 ga = sel4(a[0], a[2], a[4], a[6], sb0, sb1);
            f32x4 gb = sel4(a[1], a[3], a[5], a[7], sb0, sb1);
            f32x2 hv = cell2(ga, gb, cst2);
            hl = hv;
            f16x2 hp; hp[0] = (_Float16)hv.x; hp[1] = (_Float16)hv.y;
            *(f16x2*)(&h2s[P][0] + whofs) = hp;              // h2(t-2)
        }
        if (doL1) {
            f32x4 pre0, pre1;
            #pragma unroll
            for (int j = 0; j < 4; ++j) {
                pre0[j] = fmaf(xv, wxv[0][j], b1v[0][j]);
                pre1[j] = fmaf(xv, wxv[1][j], b1v[1][j]);
            }
            f32x4 a[8];
            #pragma unroll
            for (int kk = 0; kk < 8; ++kk) a[kk] = MFMA16(wA0[kk], B1, (kk & 1) ? pre1 : pre0);
            f32x4 ga = sel4(a[0], a[2], a[4], a[6], sb0, sb1);
            f32x4 gb = sel4(a[1], a[3], a[5], a[7], sb0, sb1);
            f32x2 hv = cell2(ga, gb, cst1);
            f16x2 hp; hp[0] = (_Float16)hv.x; hp[1] = (_Float16)hv.y;
            *(f16x2*)(&h1s[P][0] + whofs) = hp;              // h1(t)
            xv = xbufT[(t + 1) * BM + row];                  // prefetch x(t+1)
        }
        if (doP) {
            #pragma unroll
            for (int kk = 0; kk < 8; ++kk)
                Pf[kk] = MFMA16(wI1[kk], B1, (kk & 1) ? b2v[1] : b2v[0]);  // P(t-1)
        }
    };

    step(0, 0, true, false, false);
    step(1, 1, true, false, true);
    for (int tb = 2; tb < 512; tb += 2) {     // guard-free hot loop, t in [2,511]
        step(tb,     0, true, true, true);
        step(tb + 1, 1, true, true, true);
    }
    step(512, 0, false, true, true);
    step(513, 1, false, true, false);

    // ---- FC head ----
    h2f[row * 33 + (8 * s + 2 * q + 0)] = hl.x;
    h2f[row * 33 + (8 * s + 2 * q + 1)] = hl.y;
    __syncthreads();
    {
        int rr = tid >> 4, j = tid & 15;      // all 256 threads
        float acc = fc1_b[j];
        #pragma unroll
        for (int k = 0; k < H; ++k) acc += fc1_w[j * H + k] * h2f[rr * 33 + k];
        acc = acc >= 0.f ? acc : 0.2f * acc;
        yb[rr * 17 + j] = acc * fc2_w[j];
    }
    __syncthreads();
    if (tid < BM) {
        float acc = fc2_b[0];
        #pragma unroll
        for (int j = 0; j < 16; ++j) acc += yb[tid * 17 + j];
        out[r0 + tid] = acc;
    }
}

extern "C" void kernel_launch(void* const* d_in, const int* in_sizes, int n_in,
                              void* d_out, int out_size, void* d_ws, size_t ws_size,
                              hipStream_t stream) {
    const float* x     = (const float*)d_in[0];
    const float* w_ih0 = (const float*)d_in[1];
    const float* w_hh0 = (const float*)d_in[2];
    const float* b_ih0 = (const float*)d_in[3];
    const float* b_hh0 = (const float*)d_in[4];
    const float* w_ih1 = (const float*)d_in[5];
    const float* w_hh1 = (const float*)d_in[6];
    const float* b_ih1 = (const float*)d_in[7];
    const float* b_hh1 = (const float*)d_in[8];
    const float* fc1_w = (const float*)d_in[9];
    const float* fc1_b = (const float*)d_in[10];
    const float* fc2_w = (const float*)d_in[11];
    const float* fc2_b = (const float*)d_in[12];
    float* out = (float*)d_out;

    const int B = in_sizes[0] / SEQ;   // 4096
    hipLaunchKernelGGL(lstm_kernel, dim3(B / BM), dim3(NTHREADS), 0, stream,
                       x, w_ih0, w_hh0, b_ih0, b_hh0, w_ih1, w_hh1, b_ih1, b_hh1,
                       fc1_w, fc1_b, fc2_w, fc2_b, out);
}

// Round 9
// 355.245 us; speedup vs baseline: 1.0808x; 1.0808x over previous
//
#include <hip/hip_runtime.h>

#define H 32
#define SEQ 512
#define BM 16          // 16 batch rows per block = 4 row-groups x 4 rows
#define NTHREADS 512   // 8 waves: wv0-3 = L1 rows 4w.., wv4-7 = L2 same rows (lag-6)
#define HSTRIDE 40     // halves per h-row in the ring: 80B rows
#define RINGD 16       // h1 ring depth (windows); barrier every 4 windows

typedef _Float16 half8 __attribute__((ext_vector_type(8)));
typedef __attribute__((ext_vector_type(4))) float f32x4;
typedef __attribute__((ext_vector_type(2))) float f32x2;

#define L2E 1.44269504088896340736f

__device__ __forceinline__ float rcp_(float x)  { return __builtin_amdgcn_rcpf(x); }
__device__ __forceinline__ float exp2_(float x) { return __builtin_amdgcn_exp2f(x); }  // raw v_exp_f32
#define MFMA16(A, B, C) __builtin_amdgcn_mfma_f32_16x16x32_f16((A), (B), (C), 0, 0, 0)

// Two LSTM cells as a packed pair; per-element numerics identical to the verified
// scalar cell (5 v_exp + 2 v_rcp each). Verified R5/R7/R8.
__device__ __forceinline__ f32x2 cell2(const f32x4& ga, const f32x4& gb, f32x2& cst) {
    f32x2 ei = {exp2_(ga[0]), exp2_(gb[0])};
    f32x2 ef = {exp2_(ga[1]), exp2_(gb[1])};
    f32x2 eg = {exp2_(ga[2]), exp2_(gb[2])};
    f32x2 eo = {exp2_(ga[3]), exp2_(gb[3])};
    f32x2 A  = 1.f + ei, F = 1.f + ef;
    f32x2 Gp = eg + 1.f, Gm = eg - 1.f;
    f32x2 t1 = A * Gp;
    f32x2 num = __builtin_elementwise_fma(cst, t1, Gm * F);
    f32x2 den = F * t1;
    f32x2 r1 = {rcp_(den.x), rcp_(den.y)};
    f32x2 cn = num * r1;
    cst = cn;
    f32x2 arg = __builtin_elementwise_min(cn * (2.f * L2E), (f32x2)80.f);
    f32x2 ec = {exp2_(arg.x), exp2_(arg.y)};
    f32x2 dh = (1.f + eo) * (ec + 1.f);
    f32x2 r2 = {rcp_(dh.x), rcp_(dh.y)};
    return (ec - 1.f) * r2;
}

// Select one f32x4 out of 4 by 2-bit lane-varying index: 12 v_cndmask. (R8-verified)
__device__ __forceinline__ f32x4 sel4(const f32x4& a0, const f32x4& a1,
                                      const f32x4& a2, const f32x4& a3,
                                      bool s0, bool s1) {
    f32x4 r;
    #pragma unroll
    for (int j = 0; j < 4; ++j) {
        float t0 = s0 ? a1[j] : a0[j];
        float t1 = s0 ? a3[j] : a2[j];
        r[j] = s1 ? t1 : t0;
    }
    return r;
}

// Pack two f32 -> two f16 in a dword (low = .x). RTN casts, matching verified numerics.
__device__ __forceinline__ unsigned int pack2(f32x2 hv) {
    _Float16 a = (_Float16)hv.x, b = (_Float16)hv.y;
    unsigned short ua = __builtin_bit_cast(unsigned short, a);
    unsigned short ub = __builtin_bit_cast(unsigned short, b);
    return (unsigned int)ua | ((unsigned int)ub << 16);
}

// Rebuild the MFMA B-frag (h[units 8q..8q+7, own row]) from per-lane packed h pairs.
// Producer layout: lane (c,q) holds units {8*(c>>2)+2q, +1} of row c&3.
// Consumer dword j (units 8q+2j,+1 of row c&3) lives in lane 16j + 4q + (c&3).
__device__ __forceinline__ half8 bfrag(unsigned int hpk, const int* bpa) {
    union { int d[4]; half8 h; } u;
    #pragma unroll
    for (int j = 0; j < 4; ++j)
        u.d[j] = __builtin_amdgcn_ds_bpermute(bpa[j], (int)hpk);
    return u.h;
}

__global__ __launch_bounds__(NTHREADS, 2) void lstm_kernel(
    const float* __restrict__ x,      // [4096,512]
    const float* __restrict__ w_ih0,  // [128,1]
    const float* __restrict__ w_hh0,  // [128,32]
    const float* __restrict__ b_ih0, const float* __restrict__ b_hh0,
    const float* __restrict__ w_ih1,  // [128,32]
    const float* __restrict__ w_hh1,  // [128,32]
    const float* __restrict__ b_ih1, const float* __restrict__ b_hh1,
    const float* __restrict__ fc1_w,  // [16,32]
    const float* __restrict__ fc1_b,  // [16]
    const float* __restrict__ fc2_w,  // [1,16]
    const float* __restrict__ fc2_b,  // [1]
    float* __restrict__ out)          // [4096]
{
    __shared__ __align__(16) float    xbufT[(SEQ + 1) * BM];      // 32.8 KB
    __shared__ __align__(16) _Float16 ring[RINGD][BM * HSTRIDE];  // h1 ring, 20.5 KB
    __shared__ __align__(16) float    h2f[BM * 33];
    __shared__ __align__(16) float    yb[BM * 17];

    const int tid  = threadIdx.x;
    const int lane = tid & 63;
    const int wv   = tid >> 6;          // 0..7; SIMD = wv&3
    const int role = wv >> 2;           // 0 = L1 engine, 1 = L2 engine (lag-6)
    const int wl   = wv & 3;            // row-group: rows 4*wl .. 4*wl+3
    const int c    = lane & 15;         // MFMA column: row = c&3, dup group s = c>>2
    const int q    = lane >> 4;         // k-quad / D row-group
    const int s    = c >> 2;            // kept MFMA pair {2s,2s+1} -> units 8s+2q+{0,1}
    const bool sb0 = s & 1, sb1 = (s >> 1) & 1;
    const int row  = 4 * wl + (c & 3);  // batch row of this lane
    const int r0   = blockIdx.x * BM;

    // ---- stage x transposed: xbufT[s][row] ----
    {
        const int xrow = tid >> 5;          // 0..15
        const int s0_  = (tid & 31) * 16;   // 16 steps per thread
        const float* xr = x + (size_t)(r0 + xrow) * SEQ + s0_;
        #pragma unroll
        for (int i = 0; i < 16; i += 4) {
            float4 v = *(const float4*)&xr[i];
            xbufT[(s0_ + i + 0) * BM + xrow] = v.x;
            xbufT[(s0_ + i + 1) * BM + xrow] = v.y;
            xbufT[(s0_ + i + 2) * BM + xrow] = v.z;
            xbufT[(s0_ + i + 3) * BM + xrow] = v.w;
        }
    }

    // ---- W fragments (R8-verified mapping). MFMA kk: A-row r holds W row
    // (gate r&3, unit 8*(kk>>1) + 2*(r>>2) + (kk&1)). Lane keeps kk=2s,2s+1.
    // Gate scales folded (i,f,o: -L2E ; g: +2L2E) so cells use raw v_exp_f32.
    const float gsc[4] = { -L2E, -L2E, 2.f * L2E, -L2E };
    const float wsc = gsc[c & 3];
    const int kb = 8 * q;

    half8 wA[8], wB[8];                 // role 0: wA=w_hh0. role 1: wA=w_ih1, wB=w_hh1.
    f32x4 bv[2], wxv[2];
    #pragma unroll
    for (int kk = 0; kk < 8; ++kk) {
        const int worig = (c & 3) * H + 8 * (kk >> 1) + 2 * (c >> 2) + (kk & 1);
        const float* p = role ? &w_ih1[worig * H + kb] : &w_hh0[worig * H + kb];
        #pragma unroll
        for (int j = 0; j < 8; ++j) wA[kk][j] = (_Float16)(p[j] * wsc);
        if (role) {
            p = &w_hh1[worig * H + kb];
            #pragma unroll
            for (int j = 0; j < 8; ++j) wB[kk][j] = (_Float16)(p[j] * wsc);
        }
    }
    #pragma unroll
    for (int k = 0; k < 2; ++k) {
        const int u = 8 * s + 2 * q + k;
        #pragma unroll
        for (int g = 0; g < 4; ++g) {
            if (role == 0) {
                bv[k][g]  = (b_ih0[g * H + u] + b_hh0[g * H + u]) * gsc[g];
                wxv[k][g] = w_ih0[g * H + u] * gsc[g];
            } else {
                bv[k][g]  = (b_ih1[g * H + u] + b_hh1[g * H + u]) * gsc[g];
            }
        }
    }

    int bpa[4];
    #pragma unroll
    for (int j = 0; j < 4; ++j) bpa[j] = 4 * (16 * j + 4 * q + (c & 3));

    unsigned int hpk = 0;               // packed own h pair (h1(t-1) / h2(tau-1))
    f32x4 Pf[8] = {};                   // role 1: P(w-6) at window w
    f32x2 cst = {0.f, 0.f};
    f32x2 hl  = {0.f, 0.f};

    const int rdofs = row * HSTRIDE + kb;              // ring b128 read (halves)
    const int wrofs = row * HSTRIDE + 8 * s + 2 * q;   // ring dword write (halves, even)

    __syncthreads();

    float xv = xbufT[row];              // x(0) (role 0 only)

    // Window w: L1 computes h1(w) (w<512). L2: reads ring h1(w-5), computes
    // h2(w-6) = cell(Whh1 @ bperm(h2(w-7)) + P(w-6)), then Pf = P(w-5) =
    // Wih1 @ h1(w-5) + b. Barrier every 4 windows publishes the ring; skew <= 3
    // windows, ring distance 8 < 16 -> no overwrite; h1(w-5) always published.
    for (int g = 0; g < 130; ++g) {
        __syncthreads();
        #pragma unroll
        for (int j4 = 0; j4 < 4; ++j4) {
            const int w = 4 * g + j4;
            if (role == 0) {
                if (w < 512) {
                    half8 B1 = bfrag(hpk, bpa);                    // h1(w-1), own rows
                    f32x4 pre0, pre1;
                    #pragma unroll
                    for (int j = 0; j < 4; ++j) {
                        pre0[j] = fmaf(xv, wxv[0][j], bv[0][j]);
                        pre1[j] = fmaf(xv, wxv[1][j], bv[1][j]);
                    }
                    f32x4 a[8];
                    #pragma unroll
                    for (int kk = 0; kk < 8; ++kk)
                        a[kk] = MFMA16(wA[kk], B1, (kk & 1) ? pre1 : pre0);
                    f32x4 ga = sel4(a[0], a[2], a[4], a[6], sb0, sb1);
                    f32x4 gb = sel4(a[1], a[3], a[5], a[7], sb0, sb1);
                    f32x2 hv = cell2(ga, gb, cst);
                    hpk = pack2(hv);
                    *(unsigned int*)(&ring[w & (RINGD - 1)][wrofs]) = hpk;  // h1(w)
                    xv = xbufT[(w + 1) * BM + row];
                }
            } else {
                const bool doP = (w >= 5) && (w <= 516);
                const bool doH = (w >= 6) && (w <= 517);
                half8 rd = {};
                if (doP) rd = *(const half8*)(&ring[(w - 5) & (RINGD - 1)][rdofs]); // h1(w-5)
                if (doH) {
                    half8 B2 = bfrag(hpk, bpa);                    // h2(w-7), own rows
                    f32x4 a[8];
                    #pragma unroll
                    for (int kk = 0; kk < 8; ++kk)
                        a[kk] = MFMA16(wB[kk], B2, Pf[kk]);        // + P(w-6)
                    f32x4 ga = sel4(a[0], a[2], a[4], a[6], sb0, sb1);
                    f32x4 gb = sel4(a[1], a[3], a[5], a[7], sb0, sb1);
                    f32x2 hv = cell2(ga, gb, cst);
                    hl = hv;
                    hpk = pack2(hv);                               // h2(w-6)
                }
                if (doP) {
                    #pragma unroll
                    for (int kk = 0; kk < 8; ++kk)
                        Pf[kk] = MFMA16(wA[kk], rd, (kk & 1) ? bv[1] : bv[0]);  // P(w-5)
                }
            }
        }
    }

    // ---- FC head ----
    if (role == 1) {
        h2f[row * 33 + (8 * s + 2 * q + 0)] = hl.x;
        h2f[row * 33 + (8 * s + 2 * q + 1)] = hl.y;
    }
    __syncthreads();
    if (tid < BM * 16) {
        int rr = tid >> 4, j = tid & 15;
        float acc = fc1_b[j];
        #pragma unroll
        for (int k = 0; k < H; ++k) acc += fc1_w[j * H + k] * h2f[rr * 33 + k];
        acc = acc >= 0.f ? acc : 0.2f * acc;
        yb[rr * 17 + j] = acc * fc2_w[j];
    }
    __syncthreads();
    if (tid < BM) {
        float acc = fc2_b[0];
        #pragma unroll
        for (int j = 0; j < 16; ++j) acc += yb[tid * 17 + j];
        out[r0 + tid] = acc;
    }
}

extern "C" void kernel_launch(void* const* d_in, const int* in_sizes, int n_in,
                              void* d_out, int out_size, void* d_ws, size_t ws_size,
                              hipStream_t stream) {
    const float* x     = (const float*)d_in[0];
    const float* w_ih0 = (const float*)d_in[1];
    const float* w_hh0 = (const float*)d_in[2];
    const float* b_ih0 = (const float*)d_in[3];
    const float* b_hh0 = (const float*)d_in[4];
    const float* w_ih1 = (const float*)d_in[5];
    const float* w_hh1 = (const float*)d_in[6];
    const float* b_ih1 = (const float*)d_in[7];
    const float* b_hh1 = (const float*)d_in[8];
    const float* fc1_w = (const float*)d_in[9];
    const float* fc1_b = (const float*)d_in[10];
    const float* fc2_w = (const float*)d_in[11];
    const float* fc2_b = (const float*)d_in[12];
    float* out = (float*)d_out;

    const int B = in_sizes[0] / SEQ;   // 4096
    hipLaunchKernelGGL(lstm_kernel, dim3(B / BM), dim3(NTHREADS), 0, stream,
                       x, w_ih0, w_hh0, b_ih0, b_hh0, w_ih1, w_hh1, b_ih1, b_hh1,
                       fc1_w, fc1_b, fc2_w, fc2_b, out);
}

// Round 10
// 252.710 us; speedup vs baseline: 1.5193x; 1.4057x over previous
//
#include <hip/hip_runtime.h>

#define H 32
#define SEQ 512
#define BM 16          // batch rows per block (= MFMA N)
#define NTHREADS 512   // 8 waves: wv0-3 = L1 (units 8w..8w+7), wv4-7 = L2 (lag-2)
#define HSTRIDE 40     // halves per h-row: 80B rows, 16B-aligned b128 frags

typedef _Float16 half8 __attribute__((ext_vector_type(8)));
typedef _Float16 f16x2 __attribute__((ext_vector_type(2)));
typedef __attribute__((ext_vector_type(4))) float f32x4;
typedef __attribute__((ext_vector_type(2))) float f32x2;

#define L2E 1.44269504088896340736f

__device__ __forceinline__ float rcp_(float x)  { return __builtin_amdgcn_rcpf(x); }
__device__ __forceinline__ float exp2_(float x) { return __builtin_amdgcn_exp2f(x); }  // raw v_exp_f32
#define MFMA16(A, B, C) __builtin_amdgcn_mfma_f32_16x16x32_f16((A), (B), (C), 0, 0, 0)

// Two LSTM cells evaluated as a packed pair (v_pk_* f32): element 0 = cell a,
// element 1 = cell b. Per-element ops/order identical to the verified scalar cell
// (5 v_exp + 2 v_rcp each).
__device__ __forceinline__ f32x2 cell2(const f32x4& ga, const f32x4& gb, f32x2& cst) {
    f32x2 ei = {exp2_(ga[0]), exp2_(gb[0])};
    f32x2 ef = {exp2_(ga[1]), exp2_(gb[1])};
    f32x2 eg = {exp2_(ga[2]), exp2_(gb[2])};
    f32x2 eo = {exp2_(ga[3]), exp2_(gb[3])};
    f32x2 A  = 1.f + ei, F = 1.f + ef;
    f32x2 Gp = eg + 1.f, Gm = eg - 1.f;
    f32x2 t1 = A * Gp;
    f32x2 num = __builtin_elementwise_fma(cst, t1, Gm * F);
    f32x2 den = F * t1;
    f32x2 r1 = {rcp_(den.x), rcp_(den.y)};
    f32x2 cn = num * r1;
    cst = cn;
    f32x2 arg = __builtin_elementwise_min(cn * (2.f * L2E), (f32x2)80.f);
    f32x2 ec = {exp2_(arg.x), exp2_(arg.y)};
    f32x2 dh = (1.f + eo) * (ec + 1.f);
    f32x2 r2 = {rcp_(dh.x), rcp_(dh.y)};
    return (ec - 1.f) * r2;
}

__global__ __launch_bounds__(NTHREADS, 2) void lstm_kernel(
    const float* __restrict__ x,      // [4096,512]
    const float* __restrict__ w_ih0,  // [128,1]
    const float* __restrict__ w_hh0,  // [128,32]
    const float* __restrict__ b_ih0, const float* __restrict__ b_hh0,
    const float* __restrict__ w_ih1,  // [128,32]
    const float* __restrict__ w_hh1,  // [128,32]
    const float* __restrict__ b_ih1, const float* __restrict__ b_hh1,
    const float* __restrict__ fc1_w,  // [16,32]
    const float* __restrict__ fc1_b,  // [16]
    const float* __restrict__ fc2_w,  // [1,16]
    const float* __restrict__ fc2_b,  // [1]
    float* __restrict__ out)          // [4096]
{
    __shared__ __align__(16) float    xbufT[(SEQ + 1) * BM];      // +1 step pad: clampless prefetch
    __shared__ __align__(16) _Float16 h1s[4][BM * HSTRIDE];       // 4-deep h1 ring (fp16)
    __shared__ __align__(16) _Float16 h2s[2][BM * HSTRIDE];       // ping-pong h2 (fp16)
    __shared__ __align__(16) float    h2f[BM * 33];
    __shared__ __align__(16) float    yb[BM * 17];

    const int tid  = threadIdx.x;
    const int lane = tid & 63;
    const int wv   = tid >> 6;          // wave id 0..7 (wave i -> SIMD i%4)
    const int role = wv >> 2;           // 0 = layer-1 wave, 1 = layer-2 wave
    const int w    = wv & 3;            // role-local wave id 0..3: owns units 8w..8w+7
    const int c    = lane & 15;         // frag free-index / batch col
    const int q    = lane >> 4;         // k-quad / D row-group
    const int r0   = blockIdx.x * BM;

    // ---- stage x transposed: xbufT[s][row] ----
    {
        const int row = tid >> 5;           // 0..15
        const int s0  = (tid & 31) * 16;    // 16 steps per thread
        const float* xr = x + (size_t)(r0 + row) * SEQ + s0;
        #pragma unroll
        for (int i = 0; i < 16; i += 4) {
            float4 v = *(const float4*)&xr[i];
            xbufT[(s0 + i + 0) * BM + row] = v.x;
            xbufT[(s0 + i + 1) * BM + row] = v.y;
            xbufT[(s0 + i + 2) * BM + row] = v.z;
            xbufT[(s0 + i + 3) * BM + row] = v.w;
        }
    }
    for (int i = tid; i < 4 * BM * HSTRIDE; i += NTHREADS) ((_Float16*)h1s)[i] = (_Float16)0.f;
    for (int i = tid; i < 2 * BM * HSTRIDE; i += NTHREADS) ((_Float16*)h2s)[i] = (_Float16)0.f;

    // ---- W fragments (A-operand). Tile k of wave w: rows permuted
    // r -> (gate r&3, unit 8w + 2*(r>>2) + k), so lane (c,q) owns the ADJACENT
    // units 8w+2q (k=0) and 8w+2q+1 (k=1) -> single half2 h-write per step.
    // Gate scales folded (i,f,o: -L2E ; g: +2L2E) so cells use raw v_exp_f32.
    const float gsc[4] = { -L2E, -L2E, 2.f * L2E, -L2E };
    const float wsc = gsc[c & 3];
    const int kb = 8 * q;
    const int m = c;                    // batch row owned by this lane

    half8 wA[2], wB[2];                 // role 0: wA=w_hh0 ; role 1: wA=w_ih1, wB=w_hh1
    f32x4 biasv[2], wxv[2];
    #pragma unroll
    for (int k = 0; k < 2; ++k) {
        const int u     = 8 * w + 2 * q + k;            // unit of cell k for this lane
        const int worig = (c & 3) * H + 8 * w + 2 * (c >> 2) + k;
        if (role == 0) {
            const float* p = &w_hh0[worig * H + kb];
            #pragma unroll
            for (int j = 0; j < 8; ++j) wA[k][j] = (_Float16)(p[j] * wsc);
            #pragma unroll
            for (int g = 0; g < 4; ++g) {
                biasv[k][g] = (b_ih0[g * H + u] + b_hh0[g * H + u]) * gsc[g];
                wxv[k][g]   = w_ih0[g * H + u] * gsc[g];
            }
        } else {
            const float* p = &w_ih1[worig * H + kb];
            #pragma unroll
            for (int j = 0; j < 8; ++j) wA[k][j] = (_Float16)(p[j] * wsc);
            p = &w_hh1[worig * H + kb];
            #pragma unroll
            for (int j = 0; j < 8; ++j) wB[k][j] = (_Float16)(p[j] * wsc);
            #pragma unroll
            for (int g = 0; g < 4; ++g)
                biasv[k][g] = (b_ih1[g * H + u] + b_hh1[g * H + u]) * gsc[g];
        }
    }

    f32x2 cst = {0.f, 0.f};   // c-states of this lane's 2 cells
    f32x2 hl  = {0.f, 0.f};   // role 1: h2(511) per cell

    const int fofs  = c * HSTRIDE + kb;            // b128 frag read offset (halves)
    const int whofs = m * HSTRIDE + 8 * w + 2 * q; // half2 h write offset (halves, even)

    // L2 P-pipeline: P[tau&1] = W_ih1 @ h1(tau) + bias, produced at iteration
    // tau+1, consumed at iteration tau+2 (off the serial h2 chain).
    f32x4 P[2][2] = {};

    __syncthreads();

    // L1 waves carry the sequential critical chain: prefer them on the CU scheduler.
    if (role == 0) __builtin_amdgcn_s_setprio(1);

    float xv = xbufT[m];                   // prefetched x(t=0) (role-0 only uses it)

    // Iteration t: L1 computes step t (t<512); L2 finishes tau=t-2 and
    // precomputes P(t-1). h1 ring depth 4: write slot t&3=p, L1 reads (p+3)&3,
    // L2 reads (p+3)&3 (= h1(t-1)). h2 ping-pong: write (t-2)&1=p&1, read (p+1)&1.
    // P: consume [p&1], produce [(p+1)&1]. tb multiple of 4 -> all compile-time.
    for (int tb = 0; tb < 516; tb += 4) {
        #pragma unroll
        for (int p = 0; p < 4; ++p) {
            const int t = tb + p;
            if (role == 0) {
                if (t < 512) {
                    // x-term + bias pre-folded into accumulator (xv prefetched last iter)
                    f32x4 pre[2];
                    #pragma unroll
                    for (int k = 0; k < 2; ++k) {
                        #pragma unroll
                        for (int j = 0; j < 4; ++j) pre[k][j] = fmaf(xv, wxv[k][j], biasv[k][j]);
                    }
                    half8 a1 = *(const half8*)(&h1s[(p + 3) & 3][0] + fofs);   // h1(t-1)
                    f32x4 g0 = MFMA16(wA[0], a1, pre[0]);
                    f32x4 g1 = MFMA16(wA[1], a1, pre[1]);
                    f32x2 hv = cell2(g0, g1, cst);
                    f16x2 hp; hp[0] = (_Float16)hv.x; hp[1] = (_Float16)hv.y;
                    *(f16x2*)(&h1s[p][0] + whofs) = hp;                        // h1(t)
                    xv = xbufT[(t + 1) * BM + m];                              // prefetch x(t+1)
                }
            } else {
                if (t >= 2 && t < 514) {
                    // finish tau = t-2: only the h2-recurrence MFMA is on the chain
                    half8 a2 = *(const half8*)(&h2s[(p + 1) & 1][0] + fofs);   // h2(t-3)
                    f32x4 g0 = MFMA16(wB[0], a2, P[p & 1][0]);
                    f32x4 g1 = MFMA16(wB[1], a2, P[p & 1][1]);
                    f32x2 hv = cell2(g0, g1, cst);
                    hl = hv;
                    f16x2 hp; hp[0] = (_Float16)hv.x; hp[1] = (_Float16)hv.y;
                    *(f16x2*)(&h2s[p & 1][0] + whofs) = hp;                    // h2(t-2)
                }
                if (t >= 1 && t < 513) {
                    // precompute P(t-1) = W_ih1 @ h1(t-1) + bias (slack work)
                    half8 a1n = *(const half8*)(&h1s[(p + 3) & 3][0] + fofs);  // h1(t-1)
                    P[(p + 1) & 1][0] = MFMA16(wA[0], a1n, biasv[0]);
                    P[(p + 1) & 1][1] = MFMA16(wA[1], a1n, biasv[1]);
                }
            }
            __syncthreads();
        }
    }

    if (role == 0) __builtin_amdgcn_s_setprio(0);

    // ---- FC head ----
    if (role == 1) {
        h2f[m * 33 + (8 * w + 2 * q + 0)] = hl.x;
        h2f[m * 33 + (8 * w + 2 * q + 1)] = hl.y;
    }
    __syncthreads();
    if (tid < BM * 16) {
        int rr = tid >> 4, j = tid & 15;
        float acc = fc1_b[j];
        #pragma unroll
        for (int k = 0; k < H; ++k) acc += fc1_w[j * H + k] * h2f[rr * 33 + k];
        acc = acc >= 0.f ? acc : 0.2f * acc;
        yb[rr * 17 + j] = acc * fc2_w[j];
    }
    __syncthreads();
    if (tid < BM) {
        float acc = fc2_b[0];
        #pragma unroll
        for (int j = 0; j < 16; ++j) acc += yb[tid * 17 + j];
        out[r0 + tid] = acc;
    }
}

extern "C" void kernel_launch(void* const* d_in, const int* in_sizes, int n_in,
                              void* d_out, int out_size, void* d_ws, size_t ws_size,
                              hipStream_t stream) {
    const float* x     = (const float*)d_in[0];
    const float* w_ih0 = (const float*)d_in[1];
    const float* w_hh0 = (const float*)d_in[2];
    const float* b_ih0 = (const float*)d_in[3];
    const float* b_hh0 = (const float*)d_in[4];
    const float* w_ih1 = (const float*)d_in[5];
    const float* w_hh1 = (const float*)d_in[6];
    const float* b_ih1 = (const float*)d_in[7];
    const float* b_hh1 = (const float*)d_in[8];
    const float* fc1_w = (const float*)d_in[9];
    const float* fc1_b = (const float*)d_in[10];
    const float* fc2_w = (const float*)d_in[11];
    const float* fc2_b = (const float*)d_in[12];
    float* out = (float*)d_out;

    const int B = in_sizes[0] / SEQ;   // 4096
    hipLaunchKernelGGL(lstm_kernel, dim3(B / BM), dim3(NTHREADS), 0, stream,
                       x, w_ih0, w_hh0, b_ih0, b_hh0, w_ih1, w_hh1, b_ih1, b_hh1,
                       fc1_w, fc1_b, fc2_w, fc2_b, out);
}